// Round 16
// baseline (527.864 us; speedup 1.0000x reference)
//
#include <hip/hip_runtime.h>
#include <math.h>

// ChamferLoss: pred [32,4096,3] f32, gt [32,4096,3] f32 -> scalar f32.
//
// R20 = R19 (prep fused into main, total 97.8us best) + target-split for
// occupancy. R19 counters: main 48.7us, VALU busy 27.8us, MFMA 13.6us
// (exact full-rate floor), ~21us idle at Occupancy 30%. Cause: grid 512 =
// 2 blocks/CU = 4 waves/SIMD -- the GRID caps occupancy (4096 waves total
// at 64 rows/wave), not registers (VGPR 56 <= 64 permits 8 waves/SIMD per
// m69; LDS 33KB x 4 = 132KB < 160).
//  - Split the target stream in HALF per block (thalf): grid 1024 =
//    dir(2) x b(32) x panel(8) x thalf(2) = 4 blocks/CU = 32 waves/CU.
//    Block shape unchanged (8 waves x 64 rows, 2 A-frags, CHT=32, NCH=2).
//    Total staging/fold/MFMA work UNCHANGED (each block stages only its
//    own 64 tiles).
//  - Cross-thalf row-min merge: plain stores of per-row mins to wsrow
//    (2 x 256K floats); 128-block finish does sqrt(min(h0,h1)) + sum.
//    No atomics in main, no ws init, main epilogue cheaper (no sqrt/sum).
//  - __launch_bounds__(512,8): target the <=64-VGPR 8-wave/SIMD regime.
// Numerics identical (absmax 0.0 in R11-R17, R19).
//
// Layouts (m74/m101-verified, 32x32x16 bf16):
//   A: row = lane&31, k = 8*(lane>>5)+i
//   B: col = lane&31, k = 8*(lane>>5)+i
//   C: col = lane&31, row = (reg&3) + 8*(reg>>2) + 4*(lane>>5)
// K-slot map (A = -2*query split h/m, B = target split h/m):
//   k0-5: Ah*(Bh,Bm)  k6-11: Am*(Bh,Bm)  k12-13: Q2h,Q2m*1  k14-15: 1*T2h,T2m
//   => acc = d2 = q2 + t2 - 2*dot directly.

typedef short short8 __attribute__((ext_vector_type(8)));
typedef float f32x16 __attribute__((ext_vector_type(16)));
typedef unsigned int uint;

#define NPTS  4096
#define TPBM  512           // 8 waves, each owns 64 rows (2 A-frags)
#define TPBP  256
#define GRID_MAIN 1024      // dir(2) x b(32) x panel(8) x thalf(2)
#define CHT   32            // tiles per chunk (32 cols each) = 32KB staged
#define NCH   2             // 64 tiles per block (half the target stream)
#define NROWS (2 * 32 * NPTS)                // 262144 query rows total
#define ONEB ((short)0x3F80)                 // bf16 1.0

// ---- bf16 split helpers (RNE) ----
__device__ __forceinline__ unsigned short bf16h(float f) {
    uint u = __float_as_uint(f);
    uint r = u + 0x7FFFu + ((u >> 16) & 1u);
    return (unsigned short)(r >> 16);
}
__device__ __forceinline__ float bf16f(unsigned short h) {
    return __uint_as_float(((uint)h) << 16);
}
struct Split2 { unsigned short h, m; };
__device__ __forceinline__ Split2 split2(float x) {
    Split2 s;
    s.h = bf16h(x);
    s.m = bf16h(x - bf16f(s.h));
    return s;
}

// ---- main: block = (dir, b, 512 query rows, half the target tiles) ----
__global__ __launch_bounds__(TPBM, 8) void chamfer_mfma(
    const float* __restrict__ pred,
    const float* __restrict__ gt,
    float* __restrict__ wsrow)
{
    const int bx    = blockIdx.x;      // dir(2) x b(32) x panel(8) x thalf(2)
    const int dir   = bx >> 9;
    const int rem   = bx & 511;
    const int b     = rem >> 4;
    const int sub   = rem & 15;
    const int panel = sub >> 1;
    const int thalf = sub & 1;
    const int tid   = threadIdx.x;
    const int lane  = tid & 63, wid = tid >> 6;
    const int c31   = lane & 31, half = lane >> 5;

    __shared__ short8 sB[CHT * 64];   // 32 KB, shared by all 8 waves

    // dir0: queries = gt rows, targets = pred; dir1: queries = pred, targets = gt
    const float* qsrc = (dir ? pred : gt) + (size_t)b * NPTS * 3;
    const float* tsrc = (dir ? gt : pred) + (size_t)b * NPTS * 3;

    // 2 A-frags: rows panel*512 + wid*64 + fr*32 + c31; -2*coords, q2 baked.
    short8 afr[2];
    float gm[2][16];
#pragma unroll
    for (int fr = 0; fr < 2; ++fr) {
        const int row = panel * 512 + wid * 64 + fr * 32 + c31;
        const float* ap = qsrc + (size_t)row * 3;
        float x = ap[0], y = ap[1], z = ap[2];
        Split2 X = split2(-2.0f*x), Y = split2(-2.0f*y), Z = split2(-2.0f*z);
        Split2 Q2 = split2(fmaf(x, x, fmaf(y, y, z * z)));
        short8 a;
        if (half == 0) {
            a[0]=(short)X.h; a[1]=(short)Y.h; a[2]=(short)Z.h;
            a[3]=(short)X.h; a[4]=(short)Y.h; a[5]=(short)Z.h;
            a[6]=(short)X.m; a[7]=(short)Y.m;
        } else {
            a[0]=(short)Z.m; a[1]=(short)X.m; a[2]=(short)Y.m; a[3]=(short)Z.m;
            a[4]=(short)Q2.h; a[5]=(short)Q2.m; a[6]=ONEB; a[7]=ONEB;
        }
        afr[fr] = a;
#pragma unroll
        for (int r = 0; r < 16; ++r) gm[fr][r] = 1e30f;
    }

    const f32x16 zero = {0.f,0.f,0.f,0.f,0.f,0.f,0.f,0.f,
                         0.f,0.f,0.f,0.f,0.f,0.f,0.f,0.f};

    // T14 async-stage, raw form: rx/ry/rz hold the NEXT chunk's coords.
    // Entry u = ps*TPBM+tid: tile u>>6, point col u&31 (both frag halves
    // load the same point; L1 dedupes). Tiles thalf*64 + ch*CHT + (u>>6).
    const int tbase = thalf * (NCH * CHT);
    float rx[4], ry[4], rz[4];
#pragma unroll
    for (int ps = 0; ps < 4; ++ps) {
        const int u  = ps * TPBM + tid;
        const int pt = (tbase + (u >> 6)) * 32 + (u & 31);
        const float* p = tsrc + (size_t)pt * 3;
        rx[ps] = p[0]; ry[ps] = p[1]; rz[ps] = p[2];
    }

    for (int ch = 0; ch < NCH; ++ch) {
        __syncthreads();   // prior chunk's reads done
        // build fragments in-register, write to LDS
#pragma unroll
        for (int ps = 0; ps < 4; ++ps) {
            const int u = ps * TPBM + tid;
            float x = rx[ps], y = ry[ps], z = rz[ps];
            Split2 X = split2(x), Y = split2(y), Z = split2(z);
            short8 f;
            if (((u >> 5) & 1) == 0) {
                f[0]=(short)X.h; f[1]=(short)Y.h; f[2]=(short)Z.h;
                f[3]=(short)X.m; f[4]=(short)Y.m; f[5]=(short)Z.m;
                f[6]=(short)X.h; f[7]=(short)Y.h;
            } else {
                Split2 T2 = split2(fmaf(x, x, fmaf(y, y, z * z)));
                f[0]=(short)Z.h; f[1]=(short)X.m; f[2]=(short)Y.m;
                f[3]=(short)Z.m; f[4]=ONEB; f[5]=ONEB;
                f[6]=(short)T2.h; f[7]=(short)T2.m;
            }
            sB[u] = f;
        }
        __syncthreads();   // sB visible

        const int chn = (ch + 1 < NCH) ? ch + 1 : ch;   // clamp: no overread
#pragma unroll
        for (int ps = 0; ps < 4; ++ps) {
            const int u  = ps * TPBM + tid;
            const int pt = (tbase + chn * CHT + (u >> 6)) * 32 + (u & 31);
            const float* p = tsrc + (size_t)pt * 3;
            rx[ps] = p[0]; ry[ps] = p[1]; rz[ps] = p[2];
        }

        // 32 tiles: per tile 1 ds_read_b128 + 2 MFMA + 32 v_min
#pragma unroll 4
        for (int t = 0; t < CHT; ++t) {
            short8 bfr = sB[t * 64 + lane];
            f32x16 a0 = __builtin_amdgcn_mfma_f32_32x32x16_bf16(
                afr[0], bfr, zero, 0, 0, 0);
            f32x16 a1 = __builtin_amdgcn_mfma_f32_32x32x16_bf16(
                afr[1], bfr, zero, 0, 0, 0);
#pragma unroll
            for (int r = 0; r < 16; ++r) {
                gm[0][r] = fminf(gm[0][r], a0[r]);
                gm[1][r] = fminf(gm[1][r], a1[r]);
            }
        }
    }

    // Fold row-mins across the 32 target-cols (c31 lanes).
#pragma unroll
    for (int off = 1; off < 32; off <<= 1)
#pragma unroll
        for (int fr = 0; fr < 2; ++fr)
#pragma unroll
            for (int r = 0; r < 16; ++r)
                gm[fr][r] = fminf(gm[fr][r], __shfl_xor(gm[fr][r], off, 64));

    // lanes 0 and 32 hold complete row-mins (over THIS half of targets) for
    // 2x16 disjoint rows each: crow = (r&3) + 8*(r>>2) + 4*half.
    // Plain store; the two thalf blocks write disjoint ws halves.
    if (c31 == 0) {
        const int rowbase = (dir * 32 + b) * NPTS + panel * 512 + wid * 64;
        float* w = wsrow + (size_t)thalf * NROWS + rowbase;
#pragma unroll
        for (int fr = 0; fr < 2; ++fr)
#pragma unroll
            for (int r = 0; r < 16; ++r)
                w[fr * 32 + (r & 3) + 8 * (r >> 2) + 4 * half] = gm[fr][r];
    }
}

// ---- finish: merge thalf mins, sqrt, mean -> out[0] ----
__global__ __launch_bounds__(TPBP) void chamfer_finish(
    const float* __restrict__ wsrow, float* __restrict__ out)
{
    __shared__ float swv[TPBP / 64];
    const int tid  = threadIdx.x;
    const int base = blockIdx.x * (TPBP * 8) + tid;   // 128 blocks x 2048

    float s = 0.0f;
#pragma unroll
    for (int r = 0; r < 8; ++r) {
        const int i = base + r * TPBP;
        float v = fminf(wsrow[i], wsrow[NROWS + i]);
        s += sqrtf(fmaxf(v, 1e-12f));
    }

#pragma unroll
    for (int off = 32; off > 0; off >>= 1) s += __shfl_down(s, off, 64);
    const int wid = tid >> 6, lane = tid & 63;
    if (lane == 0) swv[wid] = s;
    __syncthreads();
    if (tid == 0) {
        float tot = swv[0] + swv[1] + swv[2] + swv[3];
        atomicAdd(out, tot * (1.0f / 131072.0f));
    }
}

extern "C" void kernel_launch(void* const* d_in, const int* in_sizes, int n_in,
                              void* d_out, int out_size, void* d_ws, size_t ws_size,
                              hipStream_t stream)
{
    const float* pred = (const float*)d_in[0];
    const float* gt   = (const float*)d_in[1];
    float* out        = (float*)d_out;
    float* wsrow      = (float*)d_ws;   // 2 x 262144 floats = 2MB

    hipMemsetAsync(d_out, 0, sizeof(float), stream);

    chamfer_mfma<<<dim3(GRID_MAIN), dim3(TPBM), 0, stream>>>(pred, gt, wsrow);
    chamfer_finish<<<dim3(NROWS / (TPBP * 8)), dim3(TPBP), 0, stream>>>(
        wsrow, out);
}

// Round 17
// 102.826 us; speedup vs baseline: 5.1336x; 5.1336x over previous
//
#include <hip/hip_runtime.h>
#include <math.h>

// ChamferLoss: pred [32,4096,3] f32, gt [32,4096,3] f32 -> scalar f32.
//
// R21 = R20 with the launch-bounds poison removed. R20 post-mortem:
// __launch_bounds__(512,8) on gfx950's UNIFIED VGPR/AGPR file forces
// arch+acc <= 64 regs -> allocator gave 32 arch VGPRs and spilled gm[2][16]
// to scratch: FETCH 867MB, HBM 5.1TB/s, main ~470us. The thalf-split was
// never actually tested. Fix: (512,4) (cap 128). R19 compiled to VGPR=56
// under the same bound, and 56 <= 64 still PERMITS 8 waves/SIMD by the
// hardware rule (m69: waves halve at 64/128/256) -- no coercion needed.
//  - grid 1024 = dir(2) x b(32) x panel(8) x thalf(2): 4 blocks/CU
//    (LDS 32KB x 4 = 128KB < 160), up to 32 waves/CU.
//  - Cross-thalf merge: plain stores to disjoint wsrow halves; 128-block
//    finish does sqrt(min(h0,h1)) + sum. No atomics in main, no ws init.
//  - All else identical to R19 (prep fused into staging, T14 async-stage,
//    CHT=32, fminf fold). absmax 0.0 in R11-R17, R19, R20.
//
// Layouts (m74/m101-verified, 32x32x16 bf16):
//   A: row = lane&31, k = 8*(lane>>5)+i
//   B: col = lane&31, k = 8*(lane>>5)+i
//   C: col = lane&31, row = (reg&3) + 8*(reg>>2) + 4*(lane>>5)
// K-slot map (A = -2*query split h/m, B = target split h/m):
//   k0-5: Ah*(Bh,Bm)  k6-11: Am*(Bh,Bm)  k12-13: Q2h,Q2m*1  k14-15: 1*T2h,T2m
//   => acc = d2 = q2 + t2 - 2*dot directly.

typedef short short8 __attribute__((ext_vector_type(8)));
typedef float f32x16 __attribute__((ext_vector_type(16)));
typedef unsigned int uint;

#define NPTS  4096
#define TPBM  512           // 8 waves, each owns 64 rows (2 A-frags)
#define TPBP  256
#define GRID_MAIN 1024      // dir(2) x b(32) x panel(8) x thalf(2)
#define CHT   32            // tiles per chunk (32 cols each) = 32KB staged
#define NCH   2             // 64 tiles per block (half the target stream)
#define NROWS (2 * 32 * NPTS)                // 262144 query rows total
#define ONEB ((short)0x3F80)                 // bf16 1.0

// ---- bf16 split helpers (RNE) ----
__device__ __forceinline__ unsigned short bf16h(float f) {
    uint u = __float_as_uint(f);
    uint r = u + 0x7FFFu + ((u >> 16) & 1u);
    return (unsigned short)(r >> 16);
}
__device__ __forceinline__ float bf16f(unsigned short h) {
    return __uint_as_float(((uint)h) << 16);
}
struct Split2 { unsigned short h, m; };
__device__ __forceinline__ Split2 split2(float x) {
    Split2 s;
    s.h = bf16h(x);
    s.m = bf16h(x - bf16f(s.h));
    return s;
}

// ---- main: block = (dir, b, 512 query rows, half the target tiles) ----
__global__ __launch_bounds__(TPBM, 4) void chamfer_mfma(
    const float* __restrict__ pred,
    const float* __restrict__ gt,
    float* __restrict__ wsrow)
{
    const int bx    = blockIdx.x;      // dir(2) x b(32) x panel(8) x thalf(2)
    const int dir   = bx >> 9;
    const int rem   = bx & 511;
    const int b     = rem >> 4;
    const int sub   = rem & 15;
    const int panel = sub >> 1;
    const int thalf = sub & 1;
    const int tid   = threadIdx.x;
    const int lane  = tid & 63, wid = tid >> 6;
    const int c31   = lane & 31, half = lane >> 5;

    __shared__ short8 sB[CHT * 64];   // 32 KB, shared by all 8 waves

    // dir0: queries = gt rows, targets = pred; dir1: queries = pred, targets = gt
    const float* qsrc = (dir ? pred : gt) + (size_t)b * NPTS * 3;
    const float* tsrc = (dir ? gt : pred) + (size_t)b * NPTS * 3;

    // 2 A-frags: rows panel*512 + wid*64 + fr*32 + c31; -2*coords, q2 baked.
    short8 afr[2];
    float gm[2][16];
#pragma unroll
    for (int fr = 0; fr < 2; ++fr) {
        const int row = panel * 512 + wid * 64 + fr * 32 + c31;
        const float* ap = qsrc + (size_t)row * 3;
        float x = ap[0], y = ap[1], z = ap[2];
        Split2 X = split2(-2.0f*x), Y = split2(-2.0f*y), Z = split2(-2.0f*z);
        Split2 Q2 = split2(fmaf(x, x, fmaf(y, y, z * z)));
        short8 a;
        if (half == 0) {
            a[0]=(short)X.h; a[1]=(short)Y.h; a[2]=(short)Z.h;
            a[3]=(short)X.h; a[4]=(short)Y.h; a[5]=(short)Z.h;
            a[6]=(short)X.m; a[7]=(short)Y.m;
        } else {
            a[0]=(short)Z.m; a[1]=(short)X.m; a[2]=(short)Y.m; a[3]=(short)Z.m;
            a[4]=(short)Q2.h; a[5]=(short)Q2.m; a[6]=ONEB; a[7]=ONEB;
        }
        afr[fr] = a;
#pragma unroll
        for (int r = 0; r < 16; ++r) gm[fr][r] = 1e30f;
    }

    const f32x16 zero = {0.f,0.f,0.f,0.f,0.f,0.f,0.f,0.f,
                         0.f,0.f,0.f,0.f,0.f,0.f,0.f,0.f};

    // T14 async-stage, raw form: rx/ry/rz hold the NEXT chunk's coords.
    // Entry u = ps*TPBM+tid: tile u>>6, point col u&31 (both frag halves
    // load the same point; L1 dedupes). Tiles thalf*64 + ch*CHT + (u>>6).
    const int tbase = thalf * (NCH * CHT);
    float rx[4], ry[4], rz[4];
#pragma unroll
    for (int ps = 0; ps < 4; ++ps) {
        const int u  = ps * TPBM + tid;
        const int pt = (tbase + (u >> 6)) * 32 + (u & 31);
        const float* p = tsrc + (size_t)pt * 3;
        rx[ps] = p[0]; ry[ps] = p[1]; rz[ps] = p[2];
    }

    for (int ch = 0; ch < NCH; ++ch) {
        __syncthreads();   // prior chunk's reads done
        // build fragments in-register, write to LDS
#pragma unroll
        for (int ps = 0; ps < 4; ++ps) {
            const int u = ps * TPBM + tid;
            float x = rx[ps], y = ry[ps], z = rz[ps];
            Split2 X = split2(x), Y = split2(y), Z = split2(z);
            short8 f;
            if (((u >> 5) & 1) == 0) {
                f[0]=(short)X.h; f[1]=(short)Y.h; f[2]=(short)Z.h;
                f[3]=(short)X.m; f[4]=(short)Y.m; f[5]=(short)Z.m;
                f[6]=(short)X.h; f[7]=(short)Y.h;
            } else {
                Split2 T2 = split2(fmaf(x, x, fmaf(y, y, z * z)));
                f[0]=(short)Z.h; f[1]=(short)X.m; f[2]=(short)Y.m;
                f[3]=(short)Z.m; f[4]=ONEB; f[5]=ONEB;
                f[6]=(short)T2.h; f[7]=(short)T2.m;
            }
            sB[u] = f;
        }
        __syncthreads();   // sB visible

        const int chn = (ch + 1 < NCH) ? ch + 1 : ch;   // clamp: no overread
#pragma unroll
        for (int ps = 0; ps < 4; ++ps) {
            const int u  = ps * TPBM + tid;
            const int pt = (tbase + chn * CHT + (u >> 6)) * 32 + (u & 31);
            const float* p = tsrc + (size_t)pt * 3;
            rx[ps] = p[0]; ry[ps] = p[1]; rz[ps] = p[2];
        }

        // 32 tiles: per tile 1 ds_read_b128 + 2 MFMA + 32 v_min
#pragma unroll 4
        for (int t = 0; t < CHT; ++t) {
            short8 bfr = sB[t * 64 + lane];
            f32x16 a0 = __builtin_amdgcn_mfma_f32_32x32x16_bf16(
                afr[0], bfr, zero, 0, 0, 0);
            f32x16 a1 = __builtin_amdgcn_mfma_f32_32x32x16_bf16(
                afr[1], bfr, zero, 0, 0, 0);
#pragma unroll
            for (int r = 0; r < 16; ++r) {
                gm[0][r] = fminf(gm[0][r], a0[r]);
                gm[1][r] = fminf(gm[1][r], a1[r]);
            }
        }
    }

    // Fold row-mins across the 32 target-cols (c31 lanes).
#pragma unroll
    for (int off = 1; off < 32; off <<= 1)
#pragma unroll
        for (int fr = 0; fr < 2; ++fr)
#pragma unroll
            for (int r = 0; r < 16; ++r)
                gm[fr][r] = fminf(gm[fr][r], __shfl_xor(gm[fr][r], off, 64));

    // lanes 0 and 32 hold complete row-mins (over THIS half of targets) for
    // 2x16 disjoint rows each: crow = (r&3) + 8*(r>>2) + 4*half.
    // Plain store; the two thalf blocks write disjoint ws halves.
    if (c31 == 0) {
        const int rowbase = (dir * 32 + b) * NPTS + panel * 512 + wid * 64;
        float* w = wsrow + (size_t)thalf * NROWS + rowbase;
#pragma unroll
        for (int fr = 0; fr < 2; ++fr)
#pragma unroll
            for (int r = 0; r < 16; ++r)
                w[fr * 32 + (r & 3) + 8 * (r >> 2) + 4 * half] = gm[fr][r];
    }
}

// ---- finish: merge thalf mins, sqrt, mean -> out[0] ----
__global__ __launch_bounds__(TPBP) void chamfer_finish(
    const float* __restrict__ wsrow, float* __restrict__ out)
{
    __shared__ float swv[TPBP / 64];
    const int tid  = threadIdx.x;
    const int base = blockIdx.x * (TPBP * 8) + tid;   // 128 blocks x 2048

    float s = 0.0f;
#pragma unroll
    for (int r = 0; r < 8; ++r) {
        const int i = base + r * TPBP;
        float v = fminf(wsrow[i], wsrow[NROWS + i]);
        s += sqrtf(fmaxf(v, 1e-12f));
    }

#pragma unroll
    for (int off = 32; off > 0; off >>= 1) s += __shfl_down(s, off, 64);
    const int wid = tid >> 6, lane = tid & 63;
    if (lane == 0) swv[wid] = s;
    __syncthreads();
    if (tid == 0) {
        float tot = swv[0] + swv[1] + swv[2] + swv[3];
        atomicAdd(out, tot * (1.0f / 131072.0f));
    }
}

extern "C" void kernel_launch(void* const* d_in, const int* in_sizes, int n_in,
                              void* d_out, int out_size, void* d_ws, size_t ws_size,
                              hipStream_t stream)
{
    const float* pred = (const float*)d_in[0];
    const float* gt   = (const float*)d_in[1];
    float* out        = (float*)d_out;
    float* wsrow      = (float*)d_ws;   // 2 x 262144 floats = 2MB

    hipMemsetAsync(d_out, 0, sizeof(float), stream);

    chamfer_mfma<<<dim3(GRID_MAIN), dim3(TPBM), 0, stream>>>(pred, gt, wsrow);
    chamfer_finish<<<dim3(NROWS / (TPBP * 8)), dim3(TPBP), 0, stream>>>(
        wsrow, out);
}